// Round 10
// baseline (504.828 us; speedup 1.0000x reference)
//
#include <hip/hip_runtime.h>
#include <hip/hip_bf16.h>
#include <stdint.h>

// Graph_Refine: N=8192, D=128, E=262144, P=4, eps=0.3. fp32 I/O.
// R10: R7/R8/R9 falsified store-, MFMA-, fetch- and occupancy-bound theories for
// the gemm (time pinned ~150us, all pipes idle). Surviving theory: K=512 -> only
// 8 barrier-bounded K-iters, each exposing a glds->vmcnt(0) drain with too little
// MFMA per iter to cover it. Fix: fat tiles BM=128 BN=256 BK=64, wave-tile 64x64
// (32 MFMA/wave/iter, 8x more MACs per staged byte), full grid (2048 blocks =
// exactly 8/CU, 2 resident), dense coalesced epilogue, no symmetry/transpose.
// Harness floor: ~246us poison fills (1GiB ws + 256MB out), untouchable.
#define N_NODES 8192
#define DIM     128
#define KTOT    512
#define NEDGE   262144
#define EPS     0.3f
#define FIX_DELTA 0.008f   // provable bf16-input dot bound: 2^-7*Sum|ab| <= 0.0078
#define FIX_CAP (1u << 19)
#define XCAP    (1u << 18)
#define LCAP    512
#define HASH_BITS 19
#define HASH_SLOTS (1u << HASH_BITS)

typedef unsigned int u32;
typedef unsigned short u16;
typedef __attribute__((ext_vector_type(8))) short short8;
typedef __attribute__((ext_vector_type(4))) float float4v;

// workspace layout (bytes)
#define OFF_YF  0u           // fp32 Y [8192][512] 16 MB
#define OFF_YB  16777216u    // bf16 Y  8 MB
#define OFF_CTR 25165824u    // counters: fc@0, uc@4, xc@8
#define OFF_HK  25166080u    // hash keys u32[2^19] 2 MB
#define OFF_HV  27263232u    // hash vals f32[2^19] 2 MB
#define OFF_FL  29360384u    // fixup list u32 2 MB
#define OFF_UL  31457536u    // unique list u32 1 MB
#define OFF_XL  32506112u    // exact-fallback list u32 1 MB
#define MEMSET_OFF OFF_CTR
#define MEMSET_BYTES (OFF_FL - OFF_CTR)

__device__ __forceinline__ u16 f2bf(float f) {  // RNE
    u32 b = __builtin_bit_cast(u32, f);
    b += 0x7fffu + ((b >> 16) & 1u);
    return (u16)(b >> 16);
}

// K1: reweight + L2-normalize per perspective; Y fp32 + bf16 (0.5 folds mean over P)
__global__ void prep_y(const float* __restrict__ x, const float* __restrict__ wp,
                       float* __restrict__ yf, u16* __restrict__ yb) {
    int node = blockIdx.x * 4 + (threadIdx.x >> 6);
    int lane = threadIdx.x & 63;
    float x0 = x[node * DIM + lane];
    float x1 = x[node * DIM + lane + 64];
    for (int p = 0; p < 4; ++p) {
        float v0 = x0 * wp[p * DIM + lane];
        float v1 = x1 * wp[p * DIM + lane + 64];
        float ss = v0 * v0 + v1 * v1;
        #pragma unroll
        for (int o = 1; o < 64; o <<= 1) ss += __shfl_xor(ss, o, 64);
        float scale = 0.5f / fmaxf(sqrtf(ss), 1e-12f);
        float y0 = v0 * scale, y1 = v1 * scale;
        int base = node * KTOT + p * DIM;
        yf[base + lane] = y0;       yf[base + lane + 64] = y1;
        yb[base + lane] = f2bf(y0); yb[base + lane + 64] = f2bf(y1);
    }
}

// K2: hash-aggregate duplicate edges + compact unique-slot list
__global__ void edge_insert(const int* __restrict__ idx, const float* __restrict__ w,
                            u32* __restrict__ hkey, float* __restrict__ hval,
                            u32* __restrict__ ucnt, u32* __restrict__ ulist) {
    int e = blockIdx.x * 256 + threadIdx.x;
    u32 cell = (u32)(idx[e] * N_NODES + idx[NEDGE + e]);
    float wv = w[e];
    u32 key = cell + 1u;
    u32 h = (cell * 2654435761u) >> (32 - HASH_BITS);
    while (true) {
        u32 old = atomicCAS(&hkey[h], 0u, key);
        if (old == 0u) { ulist[atomicAdd(ucnt, 1u)] = h; atomicAdd(&hval[h], wv); break; }
        if (old == key) { atomicAdd(&hval[h], wv); break; }
        h = (h + 1u) & (HASH_SLOTS - 1u);
    }
}

// K3: sim = Yb*Yb^T. BM=128 BN=256 BK=64; 512 thr / 8 waves (2x4); wave 64x64.
#define BM  128
#define BN  256
#define BK  64

__global__ __launch_bounds__(512, 4)
void gemm_sim(const u16* __restrict__ yb, float* __restrict__ out,
              u32* __restrict__ fcnt, u32* __restrict__ flst) {
    __shared__ __align__(16) u16 As[BM * BK];   // 16 KB
    __shared__ __align__(16) u16 Bs[BN * BK];   // 32 KB
    __shared__ u32 s_cnt, s_base;
    __shared__ u32 s_list[LCAP];
    int bm = blockIdx.y, bn = blockIdx.x;
    int tid = threadIdx.x;
    int lane = tid & 63, wid = tid >> 6;        // 8 waves
    int wm = wid >> 2, wn = wid & 3;            // 2x4 wave grid, 64x64 per wave
    if (tid == 0) s_cnt = 0;

    float4v acc[4][4] = {};
    const u16* arow = yb + (size_t)(bm * BM) * KTOT;
    const u16* brow = yb + (size_t)(bn * BN) * KTOT;

    for (int kt = 0; kt < KTOT / BK; ++kt) {
        __syncthreads();
        // stage A: 1024 chunks of 16B (128 rows x 8), B: 2048 chunks (256 rows x 8)
        #pragma unroll
        for (int q = 0; q < 2; ++q) {
            int c = q * 512 + tid;
            int row = c >> 3;
            int kg = (c & 7) ^ (row & 7);       // source-side XOR swizzle
            __builtin_amdgcn_global_load_lds(
                (const __attribute__((address_space(1))) void*)(const void*)(arow + (size_t)row * KTOT + kt * BK + kg * 8),
                (__attribute__((address_space(3))) void*)(void*)(As + c * 8),
                16, 0, 0);
        }
        #pragma unroll
        for (int q = 0; q < 4; ++q) {
            int c = q * 512 + tid;
            int row = c >> 3;
            int kg = (c & 7) ^ (row & 7);
            __builtin_amdgcn_global_load_lds(
                (const __attribute__((address_space(1))) void*)(const void*)(brow + (size_t)row * KTOT + kt * BK + kg * 8),
                (__attribute__((address_space(3))) void*)(void*)(Bs + c * 8),
                16, 0, 0);
        }
        __syncthreads();                        // drains vmcnt (glds)
        #pragma unroll
        for (int kk = 0; kk < 2; ++kk) {
            short8 af[4], bfr[4];
            int kg2 = kk * 4 + (lane >> 4);
            #pragma unroll
            for (int i = 0; i < 4; ++i) {
                int ra = wm * 64 + i * 16 + (lane & 15);
                af[i] = *(const short8*)&As[ra * BK + ((kg2 ^ (ra & 7)) * 8)];
            }
            #pragma unroll
            for (int j = 0; j < 4; ++j) {
                int rb = wn * 64 + j * 16 + (lane & 15);
                bfr[j] = *(const short8*)&Bs[rb * BK + ((kg2 ^ (rb & 7)) * 8)];
            }
            #pragma unroll
            for (int i = 0; i < 4; ++i)
                #pragma unroll
                for (int j = 0; j < 4; ++j)
                    acc[i][j] = __builtin_amdgcn_mfma_f32_16x16x32_bf16(
                        af[i], bfr[j], acc[i][j], 0, 0, 0);
        }
    }

    // epilogue: dense thresholded stores + knife-edge flags.
    // C/D layout: col=lane&15, row=(lane>>4)*4+reg [m89/m91]
    int quad = lane >> 4, lcol = lane & 15;
    #pragma unroll
    for (int i = 0; i < 4; ++i)
        #pragma unroll
        for (int j = 0; j < 4; ++j) {
            int gr0 = bm * BM + wm * 64 + i * 16 + quad * 4;
            int gc  = bn * BN + wn * 64 + j * 16 + lcol;
            #pragma unroll
            for (int r = 0; r < 4; ++r) {
                float s = acc[i][j][r];
                out[(size_t)(gr0 + r) * N_NODES + gc] = s > EPS ? s : 0.f;
                if (fabsf(s - EPS) < FIX_DELTA) {
                    u32 cell = (u32)((gr0 + r) * N_NODES + gc);
                    u32 li = atomicAdd(&s_cnt, 1u);
                    if (li < LCAP) s_list[li] = cell;
                    else { u32 g = atomicAdd(fcnt, 1u); if (g < FIX_CAP) flst[g] = cell; }
                }
            }
        }
    __syncthreads();
    u32 cnt = s_cnt < LCAP ? s_cnt : LCAP;
    if (tid == 0) s_base = atomicAdd(fcnt, cnt);
    __syncthreads();
    for (u32 t = tid; t < cnt; t += 512) {
        u32 g = s_base + t;
        if (g < FIX_CAP) flst[g] = s_list[t];
    }
}

// exact fp32 dot of rows i,j of Y (16-lane team)
__device__ __forceinline__ float dot_exact(const float* __restrict__ yf,
                                           u32 i, u32 j, int tl) {
    const float4v* ri = (const float4v*)(yf + (size_t)i * KTOT);
    const float4v* rj = (const float4v*)(yf + (size_t)j * KTOT);
    float4v p = {};
    #pragma unroll
    for (int q = 0; q < 8; ++q) p += ri[q * 16 + tl] * rj[q * 16 + tl];
    float s = p.x + p.y + p.z + p.w;
    #pragma unroll
    for (int o = 8; o >= 1; o >>= 1) s += __shfl_xor(s, o, 16);
    return s;
}

// K4: exact recompute of knife-edge sim cells (each orientation flagged by its own block)
__global__ void fixup(const float* __restrict__ yf, const u32* __restrict__ fcnt,
                      const u32* __restrict__ flst, float* __restrict__ out) {
    u32 count = *fcnt; if (count > FIX_CAP) count = FIX_CAP;
    int team = (blockIdx.x * 256 + threadIdx.x) >> 4;
    int tl = threadIdx.x & 15;
    int nteams = gridDim.x * 16;
    for (u32 t = team; t < count; t += nteams) {
        u32 cell = flst[t];
        u32 i = cell >> 13, j = cell & 8191u;
        float s = dot_exact(yf, i, j, tl);
        if (tl == 0) out[cell] = s > EPS ? s : 0.f;
    }
}

// K5a: O(1) per unique edge cell — reuse stored sim (decision-exact post-fixup)
__global__ void edge_fast(const u32* __restrict__ hkey, const float* __restrict__ hval,
                          const u32* __restrict__ ucnt, const u32* __restrict__ ulist,
                          float* __restrict__ out,
                          u32* __restrict__ xcnt, u32* __restrict__ xlist) {
    u32 count = *ucnt;
    for (u32 t = blockIdx.x * 256 + threadIdx.x; t < count; t += gridDim.x * 256) {
        u32 h = ulist[t];
        u32 cell = hkey[h] - 1u;
        float a = hval[h];
        float sg = out[cell];
        bool hard = (a > 1.0f) ||
                    (sg > 0.f && fabsf(sg * a - EPS) < FIX_DELTA * a + 1e-6f) ||
                    (sg == 0.f && a > 0.97f);
        if (hard) {
            u32 g = atomicAdd(xcnt, 1u);
            if (g < XCAP) xlist[g] = h;
        } else if (sg > 0.f) {
            out[cell] = sg + ((sg * a > EPS) ? a : 0.f);
        }
    }
}

// K5b: exact fallback for hard edge cells
__global__ void edge_exact(const float* __restrict__ yf, const u32* __restrict__ hkey,
                           const float* __restrict__ hval, const u32* __restrict__ xcnt,
                           const u32* __restrict__ xlist, float* __restrict__ out) {
    u32 count = *xcnt; if (count > XCAP) count = XCAP;
    int team = (blockIdx.x * 256 + threadIdx.x) >> 4;
    int tl = threadIdx.x & 15;
    int nteams = gridDim.x * 16;
    for (u32 t = team; t < count; t += nteams) {
        u32 h = xlist[t];
        u32 cell = hkey[h] - 1u;
        float a = hval[h];
        u32 i = cell >> 13, j = cell & 8191u;
        float s = dot_exact(yf, i, j, tl);
        if (tl == 0) {
            float v = s > EPS ? s : 0.f;
            if (s * a > EPS) v += a;
            out[cell] = v;
        }
    }
}

extern "C" void kernel_launch(void* const* d_in, const int* in_sizes, int n_in,
                              void* d_out, int out_size, void* d_ws, size_t ws_size,
                              hipStream_t stream) {
    const float* x  = (const float*)d_in[0];
    const int*   oi = (const int*)d_in[1];
    const float* ow = (const float*)d_in[2];
    const float* wp = (const float*)d_in[3];
    float* out = (float*)d_out;
    char* ws = (char*)d_ws;
    float* yf = (float*)(ws + OFF_YF);
    u16*   yb = (u16*)(ws + OFF_YB);
    u32*   fc = (u32*)(ws + OFF_CTR);
    u32*   uc = (u32*)(ws + OFF_CTR + 4);
    u32*   xc = (u32*)(ws + OFF_CTR + 8);
    u32*   hk = (u32*)(ws + OFF_HK);
    float* hv = (float*)(ws + OFF_HV);
    u32*   fl = (u32*)(ws + OFF_FL);
    u32*   ul = (u32*)(ws + OFF_UL);
    u32*   xl = (u32*)(ws + OFF_XL);

    prep_y<<<N_NODES / 4, 256, 0, stream>>>(x, wp, yf, yb);
    hipMemsetAsync(ws + MEMSET_OFF, 0, MEMSET_BYTES, stream);  // counters + hash
    edge_insert<<<NEDGE / 256, 256, 0, stream>>>(oi, ow, hk, hv, uc, ul);
    gemm_sim<<<dim3(N_NODES / BN, N_NODES / BM), 512, 0, stream>>>(yb, out, fc, fl);
    fixup<<<2048, 256, 0, stream>>>(yf, fc, fl, out);
    edge_fast<<<1024, 256, 0, stream>>>(hk, hv, uc, ul, out, xc, xl);
    edge_exact<<<256, 256, 0, stream>>>(yf, hk, hv, xc, xl, out);
}